// Round 16
// baseline (177.711 us; speedup 1.0000x reference)
//
#include <hip/hip_runtime.h>

#define NA 1000
#define ND 513
#define CROP 362
#define TOP 75                 // (512-362)/2
#define NPIX (CROP * CROP)     // 131044
#define NTILE 23               // ceil(362/16)
#define NCH 2
#define ALDS 640               // total LDS-arm angles
#define LCH 320                // LDS-arm angles per chunk
#define L1CH 180               // L1-arm angles per chunk
#define NGRP 20                // groups per chunk
#define GL 16                  // LDS-arm angles per group
#define G1 9                   // L1-arm angles per group
#define WIN 32                 // staged window cells

// rotation constants (double-evaluated): 4*pi/1000 and 3*pi/1000
#define C4R 0.9999210442038161f
#define S4R 0.0125660398933523f
#define C3R 0.9999555871063437f
#define S3R 0.0094246384328790f

typedef __fp16 half2_t __attribute__((ext_vector_type(2)));

// Static device buffers, fully rewritten every call (deterministic).
// g_cell[a*ND+d] = 16 B: 8 f16 batch values of detector d, angle a.
// g_part[ch][b][pix] = per-chunk partial sums (summed by combine_kernel).
__device__ float2 g_tab[NA];
__device__ uint4  g_cell[(size_t)NA * ND];
__device__ float  g_part[(size_t)NCH * 8 * NPIX];

__global__ void table_kernel() {
    int a = blockIdx.x * blockDim.x + threadIdx.x;
    if (a >= NA) return;
    double th = (double)a * (3.14159265358979323846 / (double)NA);
    float delta_f = (float)(2.0 * 0.13 / (double)(ND - 1));
    double inv = 1.0 / (double)delta_f;
    g_tab[a] = make_float2((float)(cos(th) * inv), (float)(sin(th) * inv));
}

// x[b][a][d] (b-major, f32) -> g_cell (8 f16 per det cell), RNE.
__global__ void pack_kernel(const float* __restrict__ x) {
    int t = blockIdx.x * blockDim.x + threadIdx.x;   // t = a*ND + d
    if (t >= NA * ND) return;
    const int S = NA * ND;
    unsigned int w[4];
    #pragma unroll
    for (int b = 0; b < 4; ++b) {
        half2_t h;
        h.x = (__fp16)x[(size_t)(2 * b) * S + t];
        h.y = (__fp16)x[(size_t)(2 * b + 1) * S + t];
        __builtin_memcpy(&w[b], &h, 4);
    }
    g_cell[t] = make_uint4(w[0], w[1], w[2], w[3]);
}

__device__ __forceinline__ float dot2(unsigned int pair, half2_t wp, float acc) {
    half2_t h; __builtin_memcpy(&h, &pair, 4);
    float d;
    asm("v_dot2_f32_f16 %0, %1, %2, %3" : "=v"(d) : "v"(h), "v"(wp), "v"(acc));
    return d;
}

#define ROT4(CC, SS) { float oc=CC, os=SS; CC = fmaf(oc, C4R, -(os*S4R)); SS = fmaf(oc, S4R, os*C4R); }
#define ROT3(CC, SS) { float oc=CC, os=SS; CC = fmaf(oc, C3R, -(os*S3R)); SS = fmaf(oc, S3R, os*C3R); }

// grid (23,23,2); block = 512 = 8 waves on one 16x16 tile.
// waves 0-3: LDS arm (patch w, angles [ch*320, ch*320+320))
// waves 4-7: L1  arm (patch w-4, angles [640+ch*180, +180))
// Both arms hit the same __syncthreads cadence (20 groups + fixed extras).
__global__ __launch_bounds__(512, 8) void bp_kernel() {
    __shared__ uint4 s_win[2][GL][WIN];   // 16 KB, dbuf windows; reused as f32 scratch at end
    __shared__ int   s_base[LCH];         // 1.25 KB

    int ch  = blockIdx.z;
    int A0L = ch * LCH;                   // LDS-arm chunk base
    int A0H = ALDS + ch * L1CH;           // L1-arm chunk base
    int tid = threadIdx.x;
    int bi = blockIdx.y, bj = blockIdx.x;

    const float step = (float)(0.26 / 511.0);

    // ---- per-angle window bases for the LDS arm (corner-min p, 2-cell guard) ----
    float Xa = fmaf((float)(TOP + bi * 16),      step, -0.13f);
    float Xb = fmaf((float)(TOP + bi * 16 + 15), step, -0.13f);
    float Ya = fmaf((float)(TOP + bj * 16),      step, -0.13f);
    float Yb = fmaf((float)(TOP + bj * 16 + 15), step, -0.13f);
    for (int t = tid; t < LCH; t += 512) {
        float2 cs = g_tab[A0L + t];
        float p0 = fmaf(Xa, cs.x, fmaf(Ya, cs.y, 256.0f));
        float p1 = fmaf(Xb, cs.x, fmaf(Ya, cs.y, 256.0f));
        float p2 = fmaf(Xa, cs.x, fmaf(Yb, cs.y, 256.0f));
        float p3 = fmaf(Xb, cs.x, fmaf(Yb, cs.y, 256.0f));
        float pm = fminf(fminf(p0, p1), fminf(p2, p3)) - 2.0f;
        int b = (int)floorf(pm);
        b = b < 0 ? 0 : b;
        b = b > (ND - WIN) ? (ND - WIN) : b;   // [0, 481]
        s_base[t] = b;
    }
    __syncthreads();

    // ---- pixel coords: 4 patches of 8x8; arm pairs share a patch ----
    int wave = tid >> 6, lane = tid & 63;
    int arm = wave >> 2;                   // 0 = LDS arm, 1 = L1 arm
    int pw  = wave & 3;                    // patch id
    int i = bi * 16 + (pw >> 1) * 8 + (lane >> 3);   // -> X
    int j = bj * 16 + (pw & 1) * 8 + (lane & 7);     // -> Y
    int ic = min(i, CROP - 1), jc = min(j, CROP - 1);
    float X = fmaf((float)(TOP + ic), step, -0.13f);
    float Y = fmaf((float)(TOP + jc), step, -0.13f);

    // staging assignment: thread t stages cell sc of group-angle sk (16x32 = 512)
    int sk = tid >> 5, sc = tid & 31;

    // ---- prologue: stage group 0 into buffer 0 ----
    s_win[0][sk][sc] = g_cell[(size_t)(A0L + sk) * ND + s_base[sk] + sc];
    __syncthreads();

    // ---- rotation chains (arm-dependent) ----
    float c_0, s_0, c_1, s_1, c_2, s_2, c_3 = 0.f, s_3 = 0.f;
    if (arm == 0) {
        float2 t0 = g_tab[A0L + 0], t1 = g_tab[A0L + 1];
        float2 t2 = g_tab[A0L + 2], t3 = g_tab[A0L + 3];
        c_0 = t0.x; s_0 = t0.y; c_1 = t1.x; s_1 = t1.y;
        c_2 = t2.x; s_2 = t2.y; c_3 = t3.x; s_3 = t3.y;
    } else {
        float2 t0 = g_tab[A0H + 0], t1 = g_tab[A0H + 1], t2 = g_tab[A0H + 2];
        c_0 = t0.x; s_0 = t0.y; c_1 = t1.x; s_1 = t1.y;
        c_2 = t2.x; s_2 = t2.y;
    }

    float acc0 = 0.f, acc1 = 0.f, acc2 = 0.f, acc3 = 0.f;
    float acc4 = 0.f, acc5 = 0.f, acc6 = 0.f, acc7 = 0.f;

#define PAIRS(A, B, WP)                                                  \
        acc0 = dot2(__builtin_amdgcn_perm(B.x, A.x, 0x05040100u), WP, acc0); \
        acc1 = dot2(__builtin_amdgcn_perm(B.x, A.x, 0x07060302u), WP, acc1); \
        acc2 = dot2(__builtin_amdgcn_perm(B.y, A.y, 0x05040100u), WP, acc2); \
        acc3 = dot2(__builtin_amdgcn_perm(B.y, A.y, 0x07060302u), WP, acc3); \
        acc4 = dot2(__builtin_amdgcn_perm(B.z, A.z, 0x05040100u), WP, acc4); \
        acc5 = dot2(__builtin_amdgcn_perm(B.z, A.z, 0x07060302u), WP, acc5); \
        acc6 = dot2(__builtin_amdgcn_perm(B.w, A.w, 0x05040100u), WP, acc6); \
        acc7 = dot2(__builtin_amdgcn_perm(B.w, A.w, 0x07060302u), WP, acc7);

#define LBODY(K, BASE, CC, SS)                                          \
    {                                                                   \
        float p  = fmaf(X, CC, fmaf(Y, SS, 256.0f));                    \
        float fi = floorf(p);                                           \
        float w  = p - fi;                                              \
        half2_t wp = __builtin_amdgcn_cvt_pkrtz(1.0f - w, w);           \
        int l = (int)fi - (BASE);                                       \
        const uint4* q = &s_win[cur][K][l];                             \
        uint4 A = q[0];                                                 \
        uint4 B = q[1];                                                 \
        PAIRS(A, B, wp)                                                 \
    }

#define GBODY(ROW, CC, SS)                                              \
    {                                                                   \
        float p  = fmaf(X, CC, fmaf(Y, SS, 256.0f));                    \
        float fi = floorf(p);                                           \
        float w  = p - fi;                                              \
        half2_t wp = __builtin_amdgcn_cvt_pkrtz(1.0f - w, w);           \
        const uint4* q = g_cell + (ROW) + (int)fi;                      \
        uint4 A = q[0];                                                 \
        uint4 B = q[1];                                                 \
        PAIRS(A, B, wp)                                                 \
    }

    for (int g = 0; g < NGRP; ++g) {
        int cur = g & 1;
        bool have = (g + 1) < NGRP;
        uint4 r0;
        if (have) {
            int al = (g + 1) * GL + sk;
            r0 = g_cell[(size_t)(A0L + al) * ND + s_base[al] + sc];
        }

        if (arm == 0) {
            int gb = g * GL;
            #pragma unroll
            for (int m = 0; m < 4; ++m) {
                int4 b4 = *(const int4*)(s_base + gb + m * 4);   // uniform
                LBODY(m * 4 + 0, b4.x, c_0, s_0)
                LBODY(m * 4 + 1, b4.y, c_1, s_1)
                LBODY(m * 4 + 2, b4.z, c_2, s_2)
                LBODY(m * 4 + 3, b4.w, c_3, s_3)
                ROT4(c_0, s_0) ROT4(c_1, s_1) ROT4(c_2, s_2) ROT4(c_3, s_3)
            }
        } else {
            size_t row = (size_t)(A0H + g * G1) * ND;
            #pragma unroll
            for (int m = 0; m < 3; ++m) {
                GBODY(row + (size_t)(m * 3 + 0) * ND, c_0, s_0)
                GBODY(row + (size_t)(m * 3 + 1) * ND, c_1, s_1)
                GBODY(row + (size_t)(m * 3 + 2) * ND, c_2, s_2)
                ROT3(c_0, s_0) ROT3(c_1, s_1) ROT3(c_2, s_2)
            }
        }

        if (have) s_win[cur ^ 1][sk][sc] = r0;
        __syncthreads();
    }
#undef LBODY
#undef GBODY

    // ---- in-block reduction: L1 arm -> LDS scratch, LDS arm adds + stores ----
    float* scr = (float*)s_win;            // safe: all window reads are done
    if (arm == 1) {
        float4* dst = ((float4*)scr) + (size_t)(pw * 64 + lane) * 2;
        dst[0] = make_float4(acc0, acc1, acc2, acc3);
        dst[1] = make_float4(acc4, acc5, acc6, acc7);
    }
    __syncthreads();
    if (arm == 0 && i < CROP && j < CROP) {
        const float4* src = ((const float4*)scr) + (size_t)(pw * 64 + lane) * 2;
        float4 u = src[0], v = src[1];
        float* p0 = g_part + (size_t)ch * 8 * NPIX + (size_t)i * CROP + j;
        p0[0 * NPIX] = acc0 + u.x;
        p0[1 * NPIX] = acc1 + u.y;
        p0[2 * NPIX] = acc2 + u.z;
        p0[3 * NPIX] = acc3 + u.w;
        p0[4 * NPIX] = acc4 + v.x;
        p0[5 * NPIX] = acc5 + v.y;
        p0[6 * NPIX] = acc6 + v.z;
        p0[7 * NPIX] = acc7 + v.w;
    }
}

// out[b][pix] = (part[0][b][pix] + part[1][b][pix]) * pi/NA
__global__ void combine_kernel(float* __restrict__ out) {
    int t = blockIdx.x * 256 + threadIdx.x;      // t over 8*NPIX, batch-major
    if (t >= 8 * NPIX) return;
    const float scale = (float)(3.14159265358979323846 / 1000.0);
    out[t] = (g_part[t] + g_part[(size_t)8 * NPIX + t]) * scale;
}

extern "C" void kernel_launch(void* const* d_in, const int* in_sizes, int n_in,
                              void* d_out, int out_size, void* d_ws, size_t ws_size,
                              hipStream_t stream) {
    const float* x = (const float*)d_in[0];
    float* out = (float*)d_out;

    table_kernel<<<(NA + 255) / 256, 256, 0, stream>>>();
    pack_kernel<<<(NA * ND + 255) / 256, 256, 0, stream>>>(x);

    dim3 bgrid(NTILE, NTILE, NCH);   // 23 x 23 x 2 = 1058 blocks
    bp_kernel<<<bgrid, 512, 0, stream>>>();

    combine_kernel<<<(8 * NPIX + 255) / 256, 256, 0, stream>>>(out);
}

// Round 17
// 127.420 us; speedup vs baseline: 1.3947x; 1.3947x over previous
//
#include <hip/hip_runtime.h>

#define NA 1000
#define NCH 3
#define CH0 336                // chunk lens 336,336,328 (all % 8 == 0)
#define ND 513
#define ND2 512                // pair cells per angle: d in [0,511]
#define CROP 362
#define TOP 75                 // (512-362)/2
#define NPIX (CROP * CROP)     // 131044
#define NTILE 23               // ceil(362/16)
#define GRP 8                  // angles per staged group
#define WIN 32                 // detector cells per staged window

// rotation by 4*dtheta = 4*pi/1000 (f32 literals from double eval)
#define C4R 0.9999210442038161f
#define S4R 0.0125660398933523f

typedef __fp16 half2_t __attribute__((ext_vector_type(2)));

#if defined(__has_builtin)
#if __has_builtin(__builtin_amdgcn_global_load_lds)
#define HAS_GLL 1
#endif
#endif

#ifdef HAS_GLL
// async global->LDS, 16B per lane; lptr must be wave-uniform (lane*16 added by HW)
#define GLL(G, L) __builtin_amdgcn_global_load_lds(                        \
    (const __attribute__((address_space(1))) void*)(G),                   \
    (__attribute__((address_space(3))) void*)(L), 16, 0, 0)
#endif

// Static device buffers, fully rewritten every call (deterministic).
// g_plo[a*512+d] = 16 B: f16 pairs (x[b][a][d], x[b][a][d+1]) for b=0..3.
// g_phi: same for b=4..7.  g_part: [chunk][batch][pix] f32 partials.
__device__ float2 g_tab[NA];
__device__ uint4  g_plo[(size_t)NA * ND2];
__device__ uint4  g_phi[(size_t)NA * ND2];
__device__ float  g_part[(size_t)NCH * 8 * NPIX];

__global__ void table_kernel() {
    int a = blockIdx.x * blockDim.x + threadIdx.x;
    if (a >= NA) return;
    double th = (double)a * (3.14159265358979323846 / (double)NA);
    float delta_f = (float)(2.0 * 0.13 / (double)(ND - 1));
    double inv = 1.0 / (double)delta_f;
    g_tab[a] = make_float2((float)(cos(th) * inv), (float)(sin(th) * inv));
}

// x[b][a][d] (b-major, f32) -> pre-assembled f16 interp pairs.
__global__ void pack_kernel(const float* __restrict__ x) {
    int t = blockIdx.x * blockDim.x + threadIdx.x;   // t = a*512 + d
    if (t >= NA * ND2) return;
    int a = t >> 9, d = t & 511;
    const float* p0 = x + (size_t)a * ND + d;
    const int S = NA * ND;
    unsigned int lo[4], hi[4];
    #pragma unroll
    for (int b = 0; b < 4; ++b) {
        half2_t h;
        h.x = (__fp16)p0[(size_t)b * S];
        h.y = (__fp16)p0[(size_t)b * S + 1];
        __builtin_memcpy(&lo[b], &h, 4);
        half2_t g;
        g.x = (__fp16)p0[(size_t)(b + 4) * S];
        g.y = (__fp16)p0[(size_t)(b + 4) * S + 1];
        __builtin_memcpy(&hi[b], &g, 4);
    }
    g_plo[t] = make_uint4(lo[0], lo[1], lo[2], lo[3]);
    g_phi[t] = make_uint4(hi[0], hi[1], hi[2], hi[3]);
}

__device__ __forceinline__ float dot2(unsigned int pair, half2_t wp, float acc) {
    half2_t h; __builtin_memcpy(&h, &pair, 4);
    float d;
    asm("v_dot2_f32_f16 %0, %1, %2, %3" : "=v"(d) : "v"(h), "v"(wp), "v"(acc));
    return d;
}

#define ROT4(CC, SS) { float oc=CC, os=SS; CC = fmaf(oc, C4R, -(os*S4R)); SS = fmaf(oc, S4R, os*C4R); }

// grid (23,23,3) = 1587 blocks -> all-resident at 8 blocks/CU (zero tail).
// block 256 = 4 waves of 8x8 pixel patches on one 16x16 tile.
// Double-buffered 8-angle x 32-cell windows staged via global_load_lds.
__global__ __launch_bounds__(256, 8) void bp_kernel() {
    __shared__ uint4 s_lo[2][GRP * WIN];          // 8 KB
    __shared__ uint4 s_hi[2][GRP * WIN];          // 8 KB
    __shared__ alignas(16) int s_base[CH0];       // 1.4 KB

    int ch  = blockIdx.z;
    int A0  = ch * CH0;
    int len = min(CH0, NA - A0);         // 336 or 328
    int ngrp = len >> 3;
    int tid = threadIdx.x;
    int bi  = blockIdx.y, bj = blockIdx.x;

    const float step = (float)(0.26 / 511.0);

    // ---- per-angle window bases (corner-min p, 2-cell guard) ----
    float Xa = fmaf((float)(TOP + bi * 16),      step, -0.13f);
    float Xb = fmaf((float)(TOP + bi * 16 + 15), step, -0.13f);
    float Ya = fmaf((float)(TOP + bj * 16),      step, -0.13f);
    float Yb = fmaf((float)(TOP + bj * 16 + 15), step, -0.13f);
    for (int t = tid; t < len; t += 256) {
        float2 cs = g_tab[A0 + t];
        float p0 = fmaf(Xa, cs.x, fmaf(Ya, cs.y, 256.0f));
        float p1 = fmaf(Xb, cs.x, fmaf(Ya, cs.y, 256.0f));
        float p2 = fmaf(Xa, cs.x, fmaf(Yb, cs.y, 256.0f));
        float p3 = fmaf(Xb, cs.x, fmaf(Yb, cs.y, 256.0f));
        float pm = fminf(fminf(p0, p1), fminf(p2, p3)) - 2.0f;
        int b = (int)floorf(pm);
        b = b < 0 ? 0 : b;
        b = b > (ND2 - WIN) ? (ND2 - WIN) : b;   // [0, 480]
        s_base[t] = b;
    }
    __syncthreads();

    // ---- pixel coords ----
    int wave = tid >> 6, lane = tid & 63;
    int i = bi * 16 + (wave >> 1) * 8 + (lane >> 3);   // -> X
    int j = bj * 16 + (wave & 1) * 8 + (lane & 7);     // -> Y
    int ic = min(i, CROP - 1), jc = min(j, CROP - 1);
    float X = fmaf((float)(TOP + ic), step, -0.13f);
    float Y = fmaf((float)(TOP + jc), step, -0.13f);

    // staging: thread tid stages cell (sk = angle-in-group, sc = window cell)
    int sk = tid >> 5, sc = tid & 31;
    int wb = tid & 192;                  // wave-uniform LDS cell base (wave*64)

    // ---- rotation chains: 4 chains stepping 4*dtheta ----
    float2 t0 = g_tab[A0 + 0], t1 = g_tab[A0 + 1];
    float2 t2 = g_tab[A0 + 2], t3 = g_tab[A0 + 3];
    float c_0 = t0.x, s_0 = t0.y, c_1 = t1.x, s_1 = t1.y;
    float c_2 = t2.x, s_2 = t2.y, c_3 = t3.x, s_3 = t3.y;

    // ---- prologue: stage group 0 into buffer 0 ----
    {
        size_t idx = (size_t)(A0 + sk) * ND2 + s_base[sk] + sc;
#ifdef HAS_GLL
        GLL(g_plo + idx, &s_lo[0][wb]);
        GLL(g_phi + idx, &s_hi[0][wb]);
#else
        s_lo[0][tid] = g_plo[idx];
        s_hi[0][tid] = g_phi[idx];
#endif
    }
    __syncthreads();   // drains vmcnt -> buffer 0 staged

    float acc0 = 0.f, acc1 = 0.f, acc2 = 0.f, acc3 = 0.f;
    float acc4 = 0.f, acc5 = 0.f, acc6 = 0.f, acc7 = 0.f;

#define LBODY(K, BASE, CC, SS)                                          \
    {                                                                   \
        float p  = fmaf(X, CC, fmaf(Y, SS, 256.0f));                    \
        float fi = floorf(p);                                           \
        float w  = p - fi;                                              \
        half2_t wp = __builtin_amdgcn_cvt_pkrtz(1.0f - w, w);           \
        int l = (int)fi - (BASE) + (K) * WIN;                           \
        uint4 A = blo[l];                                               \
        uint4 B = bhi[l];                                               \
        acc0 = dot2(A.x, wp, acc0);                                     \
        acc1 = dot2(A.y, wp, acc1);                                     \
        acc2 = dot2(A.z, wp, acc2);                                     \
        acc3 = dot2(A.w, wp, acc3);                                     \
        acc4 = dot2(B.x, wp, acc4);                                     \
        acc5 = dot2(B.y, wp, acc5);                                     \
        acc6 = dot2(B.z, wp, acc6);                                     \
        acc7 = dot2(B.w, wp, acc7);                                     \
    }

    for (int g = 0; g < ngrp; ++g) {
        int cur = g & 1;
        bool have = (g + 1) < ngrp;
#ifndef HAS_GLL
        uint4 r0, r1;
#endif
        if (have) {
            int ag = ((g + 1) << 3) + sk;
            size_t idx = (size_t)(A0 + ag) * ND2 + s_base[ag] + sc;
#ifdef HAS_GLL
            GLL(g_plo + idx, &s_lo[cur ^ 1][wb]);   // lands by next barrier
            GLL(g_phi + idx, &s_hi[cur ^ 1][wb]);
#else
            r0 = g_plo[idx];
            r1 = g_phi[idx];
#endif
        }

        const uint4* blo = s_lo[cur];
        const uint4* bhi = s_hi[cur];
        int gb = g << 3;
        int4 b4a = *(const int4*)(s_base + gb);       // uniform broadcast
        int4 b4b = *(const int4*)(s_base + gb + 4);

        LBODY(0, b4a.x, c_0, s_0)
        LBODY(1, b4a.y, c_1, s_1)
        LBODY(2, b4a.z, c_2, s_2)
        LBODY(3, b4a.w, c_3, s_3)
        ROT4(c_0, s_0) ROT4(c_1, s_1) ROT4(c_2, s_2) ROT4(c_3, s_3)
        LBODY(4, b4b.x, c_0, s_0)
        LBODY(5, b4b.y, c_1, s_1)
        LBODY(6, b4b.z, c_2, s_2)
        LBODY(7, b4b.w, c_3, s_3)
        ROT4(c_0, s_0) ROT4(c_1, s_1) ROT4(c_2, s_2) ROT4(c_3, s_3)

#ifndef HAS_GLL
        if (have) {
            s_lo[cur ^ 1][tid] = r0;
            s_hi[cur ^ 1][tid] = r1;
        }
#endif
        __syncthreads();   // vmcnt(0)+lgkmcnt(0) drain: next buffer staged
    }
#undef LBODY

    if (i < CROP && j < CROP) {
        float* p0 = g_part + (size_t)ch * 8 * NPIX + (size_t)i * CROP + j;
        p0[0 * NPIX] = acc0; p0[1 * NPIX] = acc1;
        p0[2 * NPIX] = acc2; p0[3 * NPIX] = acc3;
        p0[4 * NPIX] = acc4; p0[5 * NPIX] = acc5;
        p0[6 * NPIX] = acc6; p0[7 * NPIX] = acc7;
    }
}

// out[b][pix] = sum_ch part[ch][b][pix] * pi/NA
__global__ void combine_kernel(float* __restrict__ out) {
    int t = blockIdx.x * 256 + threadIdx.x;      // t over 8*NPIX, batch-major
    if (t >= 8 * NPIX) return;
    const float scale = (float)(3.14159265358979323846 / 1000.0);
    float s = 0.f;
    #pragma unroll
    for (int ch = 0; ch < NCH; ++ch) s += g_part[(size_t)ch * 8 * NPIX + t];
    out[t] = s * scale;
}

extern "C" void kernel_launch(void* const* d_in, const int* in_sizes, int n_in,
                              void* d_out, int out_size, void* d_ws, size_t ws_size,
                              hipStream_t stream) {
    const float* x = (const float*)d_in[0];
    float* out = (float*)d_out;

    table_kernel<<<(NA + 255) / 256, 256, 0, stream>>>();
    pack_kernel<<<(NA * ND2 + 255) / 256, 256, 0, stream>>>(x);

    dim3 bgrid(NTILE, NTILE, NCH);   // 23 x 23 x 3 = 1587 blocks, all-resident
    bp_kernel<<<bgrid, 256, 0, stream>>>();

    combine_kernel<<<(8 * NPIX + 255) / 256, 256, 0, stream>>>(out);
}